// Round 4
// baseline (3236.525 us; speedup 1.0000x reference)
//
#include <hip/hip_runtime.h>

#define HDIM 256
#define NPTS 16

// Fused div-free-field kernel, all-fp32 (accuracy anchor + VALU baseline).
// 4 streams (primal + 3 jacfwd tangents) share one in-place LDS activation
// buffer [stream][unit][point]. Each thread: 2 units x 8 points x 4 streams.
__global__ __launch_bounds__(256, 2) void divfree_kernel(
    const float* __restrict__ x,
    const float* __restrict__ W1, const float* __restrict__ b1,
    const float* __restrict__ W2, const float* __restrict__ b2,
    const float* __restrict__ W3, const float* __restrict__ b3,
    const float* __restrict__ Wo,
    float* __restrict__ out)
{
    __shared__ float A[4][HDIM][NPTS];   // 64 KiB

    const int t     = threadIdx.x;
    const int up    = t & 127;
    const int g     = t >> 7;       // point-group 0/1
    const int pbase = g * 8;
    const int u0    = up;
    const int u1    = up + 128;
    const size_t pt0 = (size_t)blockIdx.x * NPTS;

    // ---------------- Layer 1: x(3) -> h1(256), tangents t1_k = mask * W1[k,:]
    {
        float xv0[8], xv1[8], xv2[8];
        #pragma unroll
        for (int p = 0; p < 8; ++p) {
            const float* xp = x + (pt0 + pbase + p) * 3;
            xv0[p] = xp[0]; xv1[p] = xp[1]; xv2[p] = xp[2];
        }
        #pragma unroll
        for (int uu = 0; uu < 2; ++uu) {
            const int u = uu ? u1 : u0;
            const float w0 = W1[0*HDIM + u];
            const float w1 = W1[1*HDIM + u];
            const float w2 = W1[2*HDIM + u];
            const float bb = b1[u];
            #pragma unroll
            for (int p = 0; p < 8; ++p) {
                float pre = fmaf(xv2[p], w2, fmaf(xv1[p], w1, fmaf(xv0[p], w0, bb)));
                const bool m = pre > 0.0f;
                A[0][u][pbase+p] = m ? pre : 0.0f;
                A[1][u][pbase+p] = m ? w0  : 0.0f;
                A[2][u][pbase+p] = m ? w1  : 0.0f;
                A[3][u][pbase+p] = m ? w2  : 0.0f;
            }
        }
    }
    __syncthreads();

    // ---------------- Layers 2 and 3: [4 streams x 16 pts] @ W (256x256)
    #pragma unroll 1
    for (int layer = 0; layer < 2; ++layer) {
        const float* __restrict__ W = layer ? W3 : W2;
        const float* __restrict__ b = layer ? b3 : b2;

        float acc0[4][8];
        float acc1[4][8];
        #pragma unroll
        for (int s = 0; s < 4; ++s)
            #pragma unroll
            for (int p = 0; p < 8; ++p) { acc0[s][p] = 0.0f; acc1[s][p] = 0.0f; }

        #pragma unroll 2
        for (int k = 0; k < HDIM; ++k) {
            const float w0 = W[k*HDIM + u0];   // coalesced, L2-resident
            const float w1 = W[k*HDIM + u1];
            #pragma unroll
            for (int s = 0; s < 4; ++s) {
                // broadcast (same-address across wave) LDS reads: conflict-free
                const float4 a0 = *(const float4*)(&A[s][k][pbase]);
                const float4 a1 = *(const float4*)(&A[s][k][pbase+4]);
                const float av[8] = {a0.x,a0.y,a0.z,a0.w,a1.x,a1.y,a1.z,a1.w};
                #pragma unroll
                for (int p = 0; p < 8; ++p) {
                    acc0[s][p] = fmaf(av[p], w0, acc0[s][p]);
                    acc1[s][p] = fmaf(av[p], w1, acc1[s][p]);
                }
            }
        }
        __syncthreads();   // all reads of A done -> safe to overwrite in place

        {
            const float bb0 = b[u0];
            #pragma unroll
            for (int p = 0; p < 8; ++p) {
                const float pre = acc0[0][p] + bb0;
                const bool m = pre > 0.0f;     // fp32 mask: must match np ref
                A[0][u0][pbase+p] = m ? pre : 0.0f;
                A[1][u0][pbase+p] = m ? acc0[1][p] : 0.0f;
                A[2][u0][pbase+p] = m ? acc0[2][p] : 0.0f;
                A[3][u0][pbase+p] = m ? acc0[3][p] : 0.0f;
            }
            const float bb1 = b[u1];
            #pragma unroll
            for (int p = 0; p < 8; ++p) {
                const float pre = acc1[0][p] + bb1;
                const bool m = pre > 0.0f;
                A[0][u1][pbase+p] = m ? pre : 0.0f;
                A[1][u1][pbase+p] = m ? acc1[1][p] : 0.0f;
                A[2][u1][pbase+p] = m ? acc1[2][p] : 0.0f;
                A[3][u1][pbase+p] = m ? acc1[3][p] : 0.0f;
            }
        }
        __syncthreads();
    }

    // ---------------- Output: dc[m][kx] = t3_kx . Wo[:,m]; combine to out
    // Reuse A[0] region (primal h3 no longer needed) for the 16x9 dc block.
    float* dcs = &A[0][0][0];
    if (t < NPTS * 9) {
        const int p  = t / 9;
        const int c  = t % 9;        // c = m*3 + kx
        const int m  = c / 3;
        const int kx = c % 3;
        float sacc = 0.0f;
        #pragma unroll 4
        for (int h = 0; h < HDIM; ++h)
            sacc = fmaf(A[1+kx][h][p], Wo[h*3 + m], sacc);
        dcs[t] = sacc;               // writes into A[0] area; reads are A[1..3]
    }
    __syncthreads();
    if (t < NPTS * 3) {
        const int p = t / 3;
        const int j = t % 3;
        const float* d = &dcs[p*9];
        float v;
        if      (j == 0) v =  d[1] + d[5];   // +dc0/dx1 + dc1/dx2
        else if (j == 1) v = -d[0] + d[8];   // -dc0/dx0 + dc2/dx2
        else             v = -d[3] - d[7];   // -dc1/dx0 - dc2/dx1
        out[pt0*3 + t] = v;                  // contiguous 48-float store
    }
}

extern "C" void kernel_launch(void* const* d_in, const int* in_sizes, int n_in,
                              void* d_out, int out_size, void* d_ws, size_t ws_size,
                              hipStream_t stream) {
    const float* x  = (const float*)d_in[0];
    const float* W1 = (const float*)d_in[1];
    const float* b1 = (const float*)d_in[2];
    const float* W2 = (const float*)d_in[3];
    const float* b2 = (const float*)d_in[4];
    const float* W3 = (const float*)d_in[5];
    const float* b3 = (const float*)d_in[6];
    const float* Wo = (const float*)d_in[7];
    // d_in[8] = bo: derivative of a constant -> unused
    const int N = in_sizes[0] / 3;
    dim3 grid(N / NPTS), block(256);
    hipLaunchKernelGGL(divfree_kernel, grid, block, 0, stream,
                       x, W1, b1, W2, b2, W3, b3, Wo, (float*)d_out);
}

// Round 5
// 3094.262 us; speedup vs baseline: 1.0460x; 1.0460x over previous
//
#include <hip/hip_runtime.h>

#define HDIM 256
#define NPTS 16

// Swizzled LDS address (dword index): value (s,u,p) lives at
//   row (s*256+u) * 16 dwords, 16B-slot q' = (p>>2) ^ ((u>>2)&3), lane p&3.
// Reads in the k-loop are wave-uniform (broadcast) so the swizzle only
// affects address arithmetic; writes spread across 16 banks instead of 4.
__device__ __forceinline__ int aoff(int s, int u, int qswz, int lane) {
    return (((s << 8) | u) << 4) + (qswz << 2) + lane;
}

__global__ __launch_bounds__(256, 2) void divfree_kernel(
    const float* __restrict__ x,
    const float* __restrict__ W1, const float* __restrict__ b1,
    const float* __restrict__ W2, const float* __restrict__ b2,
    const float* __restrict__ W3, const float* __restrict__ b3,
    const float* __restrict__ Wo,
    float* __restrict__ out)
{
    __shared__ float A[4 * HDIM * NPTS];   // 64 KiB, 4 streams x 256 units x 16 pts

    const int t  = threadIdx.x;
    const int ul = t & 63;          // unit-lane: owns units 4*ul .. 4*ul+3
    const int pg = t >> 6;          // point-group: owns points 4*pg .. 4*pg+3
    const int u0 = ul << 2;
    const size_t pt0 = (size_t)blockIdx.x * NPTS;

    const int wswz = pg ^ (ul & 3); // swizzled slot for my writes ((u>>2)&3 == ul&3)

    // ---------------- Layer 1: x(3) -> h1, tangents t1_k = mask * W1[k,:]
    {
        float xv[4][3];
        #pragma unroll
        for (int p = 0; p < 4; ++p)
            #pragma unroll
            for (int d = 0; d < 3; ++d)
                xv[p][d] = x[(pt0 + (pg << 2) + p) * 3 + d];

        #pragma unroll
        for (int j = 0; j < 4; ++j) {
            const int u = u0 + j;
            const float w0 = W1[u], w1 = W1[HDIM + u], w2 = W1[2 * HDIM + u];
            const float bb = b1[u];
            float v[4][4];                       // [stream][p]
            #pragma unroll
            for (int p = 0; p < 4; ++p) {
                const float pre = fmaf(xv[p][2], w2, fmaf(xv[p][1], w1, fmaf(xv[p][0], w0, bb)));
                const bool m = pre > 0.0f;
                v[0][p] = m ? pre : 0.0f;
                v[1][p] = m ? w0  : 0.0f;
                v[2][p] = m ? w1  : 0.0f;
                v[3][p] = m ? w2  : 0.0f;
            }
            #pragma unroll
            for (int s = 0; s < 4; ++s)
                *(float4*)&A[aoff(s, u, wswz, 0)] =
                    make_float4(v[s][0], v[s][1], v[s][2], v[s][3]);
        }
    }
    __syncthreads();

    // ---------------- Layers 2 and 3
    #pragma unroll 1
    for (int layer = 0; layer < 2; ++layer) {
        const float* __restrict__ W = layer ? W3 : W2;
        const float* __restrict__ b = layer ? b3 : b2;

        float acc[4][4][4];                      // [j unit][stream][p]
        #pragma unroll
        for (int j = 0; j < 4; ++j)
            #pragma unroll
            for (int s = 0; s < 4; ++s)
                #pragma unroll
                for (int p = 0; p < 4; ++p) acc[j][s][p] = 0.0f;

        #pragma unroll 2
        for (int k = 0; k < HDIM; ++k) {
            const int q = pg ^ ((k >> 2) & 3);
            // 4 broadcast ds_read_b128 (wave-uniform address)
            const float4 a0 = *(const float4*)&A[aoff(0, k, q, 0)];
            const float4 a1 = *(const float4*)&A[aoff(1, k, q, 0)];
            const float4 a2 = *(const float4*)&A[aoff(2, k, q, 0)];
            const float4 a3 = *(const float4*)&A[aoff(3, k, q, 0)];
            // coalesced float4 weight load: W[k][4*ul .. 4*ul+3]
            const float4 wv = *(const float4*)(W + k * HDIM + u0);

            const float wj[4] = {wv.x, wv.y, wv.z, wv.w};
            const float as[4][4] = {{a0.x, a0.y, a0.z, a0.w},
                                    {a1.x, a1.y, a1.z, a1.w},
                                    {a2.x, a2.y, a2.z, a2.w},
                                    {a3.x, a3.y, a3.z, a3.w}};
            #pragma unroll
            for (int j = 0; j < 4; ++j)
                #pragma unroll
                for (int s = 0; s < 4; ++s)
                    #pragma unroll
                    for (int p = 0; p < 4; ++p)
                        acc[j][s][p] = fmaf(as[s][p], wj[j], acc[j][s][p]);
        }
        __syncthreads();   // all reads of A done -> safe to overwrite in place

        #pragma unroll
        for (int j = 0; j < 4; ++j) {
            const int u = u0 + j;
            const float bb = b[u];
            float v[4][4];
            #pragma unroll
            for (int p = 0; p < 4; ++p) {
                const float pre = acc[j][0][p] + bb;
                const bool m = pre > 0.0f;       // fp32 mask: matches np ref
                v[0][p] = m ? pre          : 0.0f;
                v[1][p] = m ? acc[j][1][p] : 0.0f;
                v[2][p] = m ? acc[j][2][p] : 0.0f;
                v[3][p] = m ? acc[j][3][p] : 0.0f;
            }
            #pragma unroll
            for (int s = 0; s < 4; ++s)
                *(float4*)&A[aoff(s, u, wswz, 0)] =
                    make_float4(v[s][0], v[s][1], v[s][2], v[s][3]);
        }
        __syncthreads();
    }

    // ---------------- Output: dc[p][m*3+kx] = t3_kx . Wo[:,m]
    // Reuse the s=0 plane (dwords 0..4095) for dc; reads touch s=1..3 only.
    float* dcs = A;
    if (t < NPTS * 9) {
        const int p  = t / 9;
        const int c  = t % 9;          // c = m*3 + kx
        const int m  = c / 3;
        const int kx = c % 3;
        const int s  = 1 + kx;
        float sacc = 0.0f;
        #pragma unroll 4
        for (int h = 0; h < HDIM; ++h) {
            const int q = (p >> 2) ^ ((h >> 2) & 3);
            sacc = fmaf(A[aoff(s, h, q, p & 3)], Wo[h * 3 + m], sacc);
        }
        dcs[t] = sacc;
    }
    __syncthreads();
    if (t < NPTS * 3) {
        const int p = t / 3;
        const int j = t % 3;
        const float* d = &dcs[p * 9];
        float v;
        if      (j == 0) v =  d[1] + d[5];   // +dc0/dx1 + dc1/dx2
        else if (j == 1) v = -d[0] + d[8];   // -dc0/dx0 + dc2/dx2
        else             v = -d[3] - d[7];   // -dc1/dx0 - dc2/dx1
        out[pt0 * 3 + t] = v;                // contiguous 48-float store
    }
}

extern "C" void kernel_launch(void* const* d_in, const int* in_sizes, int n_in,
                              void* d_out, int out_size, void* d_ws, size_t ws_size,
                              hipStream_t stream) {
    const float* x  = (const float*)d_in[0];
    const float* W1 = (const float*)d_in[1];
    const float* b1 = (const float*)d_in[2];
    const float* W2 = (const float*)d_in[3];
    const float* b2 = (const float*)d_in[4];
    const float* W3 = (const float*)d_in[5];
    const float* b3 = (const float*)d_in[6];
    const float* Wo = (const float*)d_in[7];
    // d_in[8] = bo: derivative of a constant -> unused
    const int N = in_sizes[0] / 3;
    dim3 grid(N / NPTS), block(256);
    hipLaunchKernelGGL(divfree_kernel, grid, block, 0, stream,
                       x, W1, b1, W2, b2, W3, b3, Wo, (float*)d_out);
}

// Round 6
// 1421.004 us; speedup vs baseline: 2.2776x; 2.1775x over previous
//
#include <hip/hip_runtime.h>

#define HDIM 256
#define NPTS 16

typedef __attribute__((ext_vector_type(8))) short bf16x8;
typedef __attribute__((ext_vector_type(4))) float f32x4;

__device__ __forceinline__ unsigned short f2bf(float f) {
    union { float f; unsigned u; } c{f};
    const unsigned r = c.u + 0x7FFFu + ((c.u >> 16) & 1u);   // RNE
    return (unsigned short)(r >> 16);
}
__device__ __forceinline__ float bf2f(unsigned short b) {
    union { unsigned u; float f; } c{((unsigned)b) << 16};
    return c.f;
}

// Primal activations H (fp32), dword offset: 16B-slot swizzle (p>>2)^((u>>2)&3)
__device__ __forceinline__ int hoff(int u, int p) {
    return (u << 4) + ((((p >> 2) ^ ((u >> 2) & 3)) & 3) << 2) + (p & 3);
}
// Tangent T (bf16) [kx][p][u], ushort offset, XOR-swizzled for conflict-free
// b128 reads along u (lanes p=0..15 at same u-slot spread over 8 banksets).
__device__ __forceinline__ int toff(int kx, int p, int u) {
    return (((((kx << 4) + p) << 8) + u)) ^ ((p & 7) << 3);
}

// ---------------------------------------------------------------------------
// Prep: W2,W3 (fp32 [k][u]) -> bf16 fragment-ordered Wt in d_ws.
// Fragment layout: Wt[mat][ut][kc][lane][i] with u = ut*16 + (lane&15),
// k = kc*32 + 8*(lane>>4) + i  — identical k(lane,i) mapping as the LDS
// B-frag reads, so the MFMA result is invariant to the HW's k ordering.
__global__ void prep_kernel(const float* __restrict__ W2,
                            const float* __restrict__ W3,
                            unsigned short* __restrict__ Wt)
{
    const int l   = threadIdx.x;          // 64
    const int bid = blockIdx.x;           // 256 = 2 mats x 16 ut x 8 kc
    const int mat = bid >> 7;
    const int ut  = (bid >> 3) & 15;
    const int kc  = bid & 7;
    const float* __restrict__ W = mat ? W3 : W2;
    const int u  = (ut << 4) + (l & 15);
    const int k0 = (kc << 5) + ((l >> 4) << 3);
    unsigned short v[8];
    #pragma unroll
    for (int i = 0; i < 8; ++i) v[i] = f2bf(W[(k0 + i) * HDIM + u]);
    unsigned short* dst = Wt + (size_t)mat * (HDIM * HDIM)
                             + (size_t)(((((ut << 3) + kc) << 6) + l) << 3);
    *(uint4*)dst = make_uint4((unsigned)v[0] | ((unsigned)v[1] << 16),
                              (unsigned)v[2] | ((unsigned)v[3] << 16),
                              (unsigned)v[4] | ((unsigned)v[5] << 16),
                              (unsigned)v[6] | ((unsigned)v[7] << 16));
}

// ---------------------------------------------------------------------------
// Main: fp32 VALU primal (exact masks) + bf16 MFMA tangents.
__global__ __launch_bounds__(256, 3) void divfree_kernel(
    const float* __restrict__ x,
    const float* __restrict__ W1, const float* __restrict__ b1,
    const float* __restrict__ W2, const float* __restrict__ b2,
    const float* __restrict__ W3, const float* __restrict__ b3,
    const float* __restrict__ Wo,
    const unsigned short* __restrict__ Wt,
    float* __restrict__ out)
{
    __shared__ __align__(16) float          H[HDIM * NPTS];      // 16 KB fp32
    __shared__ __align__(16) unsigned short T[3 * NPTS * HDIM];  // 24 KB bf16

    const int t  = threadIdx.x;
    const int ul = t & 63;          // lane in wave; also unit-lane for primal
    const int pg = t >> 6;          // wave id; also point-group for primal
    const int u0 = ul << 2;
    const size_t pt0 = (size_t)blockIdx.x * NPTS;
    const int wswz = pg ^ (ul & 3);

    // ------------- Layer 1: pre = x@W1+b1; H = relu; T[kx] = mask * W1[kx]
    {
        float xv[4][3];
        #pragma unroll
        for (int p = 0; p < 4; ++p)
            #pragma unroll
            for (int d = 0; d < 3; ++d)
                xv[p][d] = x[(pt0 + (pg << 2) + p) * 3 + d];

        #pragma unroll
        for (int j = 0; j < 4; ++j) {
            const int u = u0 + j;
            const float w0 = W1[u], w1 = W1[HDIM + u], w2 = W1[2 * HDIM + u];
            const float bb = b1[u];
            const unsigned short bw[3] = {f2bf(w0), f2bf(w1), f2bf(w2)};
            float hv[4];
            bool  m[4];
            #pragma unroll
            for (int p = 0; p < 4; ++p) {
                const float pre = fmaf(xv[p][2], w2, fmaf(xv[p][1], w1, fmaf(xv[p][0], w0, bb)));
                m[p]  = pre > 0.0f;
                hv[p] = m[p] ? pre : 0.0f;
            }
            *(float4*)&H[(u << 4) + (wswz << 2)] = make_float4(hv[0], hv[1], hv[2], hv[3]);
            // tangent init: per (kx, p) scalar u16 store of mask? W1 : 0
            #pragma unroll
            for (int kx = 0; kx < 3; ++kx)
                #pragma unroll
                for (int p = 0; p < 4; ++p)
                    T[toff(kx, (pg << 2) + p, u)] = m[p] ? bw[kx] : (unsigned short)0;
        }
    }
    __syncthreads();

    // ------------- Layers 2 and 3
    #pragma unroll 1
    for (int layer = 0; layer < 2; ++layer) {
        const float* __restrict__ W = layer ? W3 : W2;
        const float* __restrict__ b = layer ? b3 : b2;
        const unsigned short* __restrict__ Wtl = Wt + (size_t)layer * (HDIM * HDIM);

        // --- primal k-loop (fp32 VALU, exact)
        float acc[4][4];
        #pragma unroll
        for (int j = 0; j < 4; ++j)
            #pragma unroll
            for (int p = 0; p < 4; ++p) acc[j][p] = 0.0f;

        #pragma unroll 4
        for (int k = 0; k < HDIM; ++k) {
            const int q = pg ^ ((k >> 2) & 3);
            const float4 a  = *(const float4*)&H[(k << 4) + (q << 2)];  // broadcast
            const float4 wv = *(const float4*)(W + k * HDIM + u0);      // coalesced
            const float av[4] = {a.x, a.y, a.z, a.w};
            const float wj[4] = {wv.x, wv.y, wv.z, wv.w};
            #pragma unroll
            for (int j = 0; j < 4; ++j)
                #pragma unroll
                for (int p = 0; p < 4; ++p)
                    acc[j][p] = fmaf(av[p], wj[j], acc[j][p]);
        }
        __syncthreads();                 // all reads of old H done

        // --- primal epilogue: H' = relu(acc + b)  (masks for this layer)
        #pragma unroll
        for (int j = 0; j < 4; ++j) {
            const int u = u0 + j;
            const float bb = b[u];
            float hv[4];
            #pragma unroll
            for (int p = 0; p < 4; ++p) {
                const float pre = acc[j][p] + bb;
                hv[p] = pre > 0.0f ? pre : 0.0f;
            }
            *(float4*)&H[(u << 4) + (wswz << 2)] = make_float4(hv[0], hv[1], hv[2], hv[3]);
        }
        __syncthreads();                 // H' visible for mask reads

        // --- tangent streams (bf16 MFMA), one kx at a time (register-lean)
        const int lp = ul & 15, lg = ul >> 4;
        #pragma unroll 1
        for (int kx = 0; kx < 3; ++kx) {
            f32x4 acc4[4];
            #pragma unroll
            for (int n = 0; n < 4; ++n) acc4[n] = (f32x4){0.f, 0.f, 0.f, 0.f};

            #pragma unroll
            for (int kc = 0; kc < 8; ++kc) {
                // B-frag: T[kx][p=lane&15][kc*32 + 8*(lane>>4) .. +7]
                const int bidx = toff(kx, lp, (kc << 5) + (lg << 3));
                const bf16x8 bfrag = *(const bf16x8*)&T[bidx];
                #pragma unroll
                for (int n = 0; n < 4; ++n) {
                    const int ut = (pg << 2) + n;
                    const bf16x8 afrag = *(const bf16x8*)(
                        Wtl + (size_t)(((((ut << 3) + kc) << 6) + ul) << 3));
                    acc4[n] = __builtin_amdgcn_mfma_f32_16x16x32_bf16(
                        afrag, bfrag, acc4[n], 0, 0, 0);
                }
            }
            __syncthreads();             // all waves done reading T[kx]

            // epilogue: lane holds D[u = ut*16+4*lg+i][p = lp]; mask by H'>0
            #pragma unroll
            for (int n = 0; n < 4; ++n) {
                const int ub = (((pg << 2) + n) << 4) + (lg << 2);
                unsigned short vs[4];
                #pragma unroll
                for (int i = 0; i < 4; ++i) {
                    const float hp = H[hoff(ub + i, lp)];
                    vs[i] = (hp > 0.0f) ? f2bf(acc4[n][i]) : (unsigned short)0;
                }
                *(uint2*)&T[toff(kx, lp, ub)] = make_uint2(
                    (unsigned)vs[0] | ((unsigned)vs[1] << 16),
                    (unsigned)vs[2] | ((unsigned)vs[3] << 16));
            }
            // no barrier: next kx reads a disjoint T region; the next
            // layer's two barriers fence T' before any re-read.
        }
    }
    __syncthreads();                     // T' (layer 3 tangents) complete

    // ------------- Output: dc[p][m*3+kx] = T3[kx][p][:] . Wo[:,m]
    float* dcs = H;                      // primal H no longer needed
    if (t < NPTS * 9) {
        const int p  = t / 9;
        const int c  = t % 9;            // c = m*3 + kx
        const int m  = c / 3;
        const int kx = c % 3;
        float sacc = 0.0f;
        #pragma unroll 4
        for (int h = 0; h < HDIM; ++h)
            sacc = fmaf(bf2f(T[toff(kx, p, h)]), Wo[h * 3 + m], sacc);
        dcs[t] = sacc;
    }
    __syncthreads();
    if (t < NPTS * 3) {
        const int p = t / 3;
        const int j = t % 3;
        const float* d = &dcs[p * 9];
        float v;
        if      (j == 0) v =  d[1] + d[5];   // +dc0/dx1 + dc1/dx2
        else if (j == 1) v = -d[0] + d[8];   // -dc0/dx0 + dc2/dx2
        else             v = -d[3] - d[7];   // -dc1/dx0 - dc2/dx1
        out[pt0 * 3 + t] = v;
    }
}

extern "C" void kernel_launch(void* const* d_in, const int* in_sizes, int n_in,
                              void* d_out, int out_size, void* d_ws, size_t ws_size,
                              hipStream_t stream) {
    const float* x  = (const float*)d_in[0];
    const float* W1 = (const float*)d_in[1];
    const float* b1 = (const float*)d_in[2];
    const float* W2 = (const float*)d_in[3];
    const float* b2 = (const float*)d_in[4];
    const float* W3 = (const float*)d_in[5];
    const float* b3 = (const float*)d_in[6];
    const float* Wo = (const float*)d_in[7];
    // d_in[8] = bo: derivative of a constant -> unused
    unsigned short* Wt = (unsigned short*)d_ws;   // 256 KB: bf16 W2^T, W3^T frags
    const int N = in_sizes[0] / 3;

    hipLaunchKernelGGL(prep_kernel, dim3(256), dim3(64), 0, stream, W2, W3, Wt);
    hipLaunchKernelGGL(divfree_kernel, dim3(N / NPTS), dim3(256), 0, stream,
                       x, W1, b1, W2, b2, W3, b3, Wo, Wt, (float*)d_out);
}

// Round 9
// 1321.841 us; speedup vs baseline: 2.4485x; 1.0750x over previous
//
#include <hip/hip_runtime.h>

#define HDIM 256
#define NPTS 16

typedef __attribute__((ext_vector_type(8))) short bf16x8;
typedef __attribute__((ext_vector_type(4))) float f32x4;

__device__ __forceinline__ unsigned short f2bf(float f) {
    union { float f; unsigned u; } c{f};
    const unsigned r = c.u + 0x7FFFu + ((c.u >> 16) & 1u);   // RNE
    return (unsigned short)(r >> 16);
}
__device__ __forceinline__ float bf2f(unsigned short b) {
    union { unsigned u; float f; } c{((unsigned)b) << 16};
    return c.f;
}

// Primal activations H (fp32), dword offset: 16B-slot swizzle (p>>2)^((u>>2)&3)
__device__ __forceinline__ int hoff(int u, int p) {
    return (u << 4) + ((((p >> 2) ^ ((u >> 2) & 3)) & 3) << 2) + (p & 3);
}
// Tangent T (bf16) [kx][p][u], ushort offset, XOR-swizzled for conflict-free
// b128 reads along u (lanes p=0..15 at same u-slot spread over 8 banksets).
__device__ __forceinline__ int toff(int kx, int p, int u) {
    return (((((kx << 4) + p) << 8) + u)) ^ ((p & 7) << 3);
}

// ---------------------------------------------------------------------------
// Prep: W2,W3 (fp32 [k][u]) -> bf16 fragment-ordered Wt in d_ws.
// Wt[mat][ut][kc][lane][i], u = ut*16 + (lane&15), k = kc*32 + 8*(lane>>4) + i
// — same k(lane,i) mapping as the LDS B-frag reads, so HW k-order cancels.
__global__ void prep_kernel(const float* __restrict__ W2,
                            const float* __restrict__ W3,
                            unsigned short* __restrict__ Wt)
{
    const int l   = threadIdx.x;          // 64
    const int bid = blockIdx.x;           // 256 = 2 mats x 16 ut x 8 kc
    const int mat = bid >> 7;
    const int ut  = (bid >> 3) & 15;
    const int kc  = bid & 7;
    const float* __restrict__ W = mat ? W3 : W2;
    const int u  = (ut << 4) + (l & 15);
    const int k0 = (kc << 5) + ((l >> 4) << 3);
    unsigned short v[8];
    #pragma unroll
    for (int i = 0; i < 8; ++i) v[i] = f2bf(W[(k0 + i) * HDIM + u]);
    unsigned short* dst = Wt + (size_t)mat * (HDIM * HDIM)
                             + (size_t)(((((ut << 3) + kc) << 6) + l) << 3);
    *(uint4*)dst = make_uint4((unsigned)v[0] | ((unsigned)v[1] << 16),
                              (unsigned)v[2] | ((unsigned)v[3] << 16),
                              (unsigned)v[4] | ((unsigned)v[5] << 16),
                              (unsigned)v[6] | ((unsigned)v[7] << 16));
}

// ---------------------------------------------------------------------------
// Main: fp32 VALU primal (exact masks) + bf16 MFMA tangents.
__global__ __launch_bounds__(256, 3) void divfree_kernel(
    const float* __restrict__ x,
    const float* __restrict__ W1, const float* __restrict__ b1,
    const float* __restrict__ W2, const float* __restrict__ b2,
    const float* __restrict__ W3, const float* __restrict__ b3,
    const float* __restrict__ Wo,
    const unsigned short* __restrict__ Wt,
    float* __restrict__ out)
{
    __shared__ __align__(16) float          H[HDIM * NPTS];      // 16 KB fp32
    __shared__ __align__(16) unsigned short T[3 * NPTS * HDIM];  // 24 KB bf16

    const int t  = threadIdx.x;
    const int ul = t & 63;          // lane in wave; also unit-lane for primal
    const int pg = t >> 6;          // wave id; also point-group for primal
    const int u0 = ul << 2;
    const size_t pt0 = (size_t)blockIdx.x * NPTS;
    const int wswz = pg ^ (ul & 3);

    // ------------- Layer 1: pre = x@W1+b1; H = relu; T[kx] = mask * W1[kx]
    {
        float xv[4][3];
        #pragma unroll
        for (int p = 0; p < 4; ++p)
            #pragma unroll
            for (int d = 0; d < 3; ++d)
                xv[p][d] = x[(pt0 + (pg << 2) + p) * 3 + d];

        #pragma unroll
        for (int j = 0; j < 4; ++j) {
            const int u = u0 + j;
            const float w0 = W1[u], w1 = W1[HDIM + u], w2 = W1[2 * HDIM + u];
            const float bb = b1[u];
            const unsigned short bw[3] = {f2bf(w0), f2bf(w1), f2bf(w2)};
            float hv[4];
            bool  m[4];
            #pragma unroll
            for (int p = 0; p < 4; ++p) {
                const float pre = fmaf(xv[p][2], w2, fmaf(xv[p][1], w1, fmaf(xv[p][0], w0, bb)));
                m[p]  = pre > 0.0f;
                hv[p] = m[p] ? pre : 0.0f;
            }
            *(float4*)&H[(u << 4) + (wswz << 2)] = make_float4(hv[0], hv[1], hv[2], hv[3]);
            // tangent init: per (kx, p) scalar u16 store of mask? W1 : 0
            #pragma unroll
            for (int kx = 0; kx < 3; ++kx)
                #pragma unroll
                for (int p = 0; p < 4; ++p)
                    T[toff(kx, (pg << 2) + p, u)] = m[p] ? bw[kx] : (unsigned short)0;
        }
    }
    __syncthreads();

    // ------------- Layers 2 and 3
    #pragma unroll 1
    for (int layer = 0; layer < 2; ++layer) {
        const float* __restrict__ W = layer ? W3 : W2;
        const float* __restrict__ b = layer ? b3 : b2;
        const unsigned short* __restrict__ Wtl = Wt + (size_t)layer * (HDIM * HDIM);

        // --- primal k-loop (fp32 VALU, exact)
        float acc[4][4];
        #pragma unroll
        for (int j = 0; j < 4; ++j)
            #pragma unroll
            for (int p = 0; p < 4; ++p) acc[j][p] = 0.0f;

        #pragma unroll 4
        for (int k = 0; k < HDIM; ++k) {
            const int q = pg ^ ((k >> 2) & 3);
            const float4 a  = *(const float4*)&H[(k << 4) + (q << 2)];  // broadcast
            const float4 wv = *(const float4*)(W + k * HDIM + u0);      // coalesced
            const float av[4] = {a.x, a.y, a.z, a.w};
            const float wj[4] = {wv.x, wv.y, wv.z, wv.w};
            #pragma unroll
            for (int j = 0; j < 4; ++j)
                #pragma unroll
                for (int p = 0; p < 4; ++p)
                    acc[j][p] = fmaf(av[p], wj[j], acc[j][p]);
        }
        __syncthreads();                 // all reads of old H done

        // --- primal epilogue: H' = relu(acc + b)  (masks for this layer)
        #pragma unroll
        for (int j = 0; j < 4; ++j) {
            const int u = u0 + j;
            const float bb = b[u];
            float hv[4];
            #pragma unroll
            for (int p = 0; p < 4; ++p) {
                const float pre = acc[j][p] + bb;
                hv[p] = pre > 0.0f ? pre : 0.0f;
            }
            *(float4*)&H[(u << 4) + (wswz << 2)] = make_float4(hv[0], hv[1], hv[2], hv[3]);
        }
        __syncthreads();                 // H' visible for mask reads

        // --- tangent streams (bf16 MFMA), one kx at a time (register-lean)
        const int lp = ul & 15, lg = ul >> 4;
        #pragma unroll 1
        for (int kx = 0; kx < 3; ++kx) {
            f32x4 acc4[4];
            #pragma unroll
            for (int n = 0; n < 4; ++n) acc4[n] = (f32x4){0.f, 0.f, 0.f, 0.f};

            #pragma unroll
            for (int kc = 0; kc < 8; ++kc) {
                // B-frag: T[kx][p=lane&15][kc*32 + 8*(lane>>4) .. +7]
                const int bidx = toff(kx, lp, (kc << 5) + (lg << 3));
                const bf16x8 bfrag = *(const bf16x8*)&T[bidx];
                #pragma unroll
                for (int n = 0; n < 4; ++n) {
                    const int ut = (pg << 2) + n;
                    const bf16x8 afrag = *(const bf16x8*)(
                        Wtl + (size_t)(((((ut << 3) + kc) << 6) + ul) << 3));
                    acc4[n] = __builtin_amdgcn_mfma_f32_16x16x32_bf16(
                        afrag, bfrag, acc4[n], 0, 0, 0);
                }
            }
            __syncthreads();             // all waves done reading T[kx]

            // epilogue: lane holds D[u = ut*16+4*lg+i][p = lp]; mask by H'>0
            #pragma unroll
            for (int n = 0; n < 4; ++n) {
                const int ub = (((pg << 2) + n) << 4) + (lg << 2);
                unsigned short vs[4];
                #pragma unroll
                for (int i = 0; i < 4; ++i) {
                    const float hp = H[hoff(ub + i, lp)];
                    vs[i] = (hp > 0.0f) ? f2bf(acc4[n][i]) : (unsigned short)0;
                }
                *(uint2*)&T[toff(kx, lp, ub)] = make_uint2(
                    (unsigned)vs[0] | ((unsigned)vs[1] << 16),
                    (unsigned)vs[2] | ((unsigned)vs[3] << 16));
            }
            // no barrier: next kx reads a disjoint T region; the next
            // layer's two barriers fence T' before any re-read.
        }
    }
    __syncthreads();                     // T' (layer-3 tangents) complete

    // ------------- Output: all 256 threads; thread = (point p, h-chunk hg)
    {
        const int p  = t >> 4;           // 0..15
        const int hg = t & 15;           // h in [16hg, 16hg+16)
        float wo_[48];
        const float4* wp4 = (const float4*)(Wo + hg * 48);
        #pragma unroll
        for (int i = 0; i < 12; ++i) *(float4*)&wo_[4 * i] = wp4[i];

        float s[3][3];                   // [kx][m]
        #pragma unroll
        for (int kx = 0; kx < 3; ++kx)
            #pragma unroll
            for (int mm = 0; mm < 3; ++mm) s[kx][mm] = 0.0f;

        #pragma unroll
        for (int kx = 0; kx < 3; ++kx) {
            const int bidx = (((kx << 4) + p) << 8) + (hg << 4);
            const int sw   = (p & 7) << 3;
            const bf16x8 t0 = *(const bf16x8*)&T[bidx ^ sw];
            const bf16x8 t1 = *(const bf16x8*)&T[(bidx + 8) ^ sw];
            #pragma unroll
            for (int i = 0; i < 8; ++i) {
                const float f = bf2f((unsigned short)t0[i]);
                #pragma unroll
                for (int mm = 0; mm < 3; ++mm)
                    s[kx][mm] = fmaf(f, wo_[i * 3 + mm], s[kx][mm]);
            }
            #pragma unroll
            for (int i = 0; i < 8; ++i) {
                const float f = bf2f((unsigned short)t1[i]);
                #pragma unroll
                for (int mm = 0; mm < 3; ++mm)
                    s[kx][mm] = fmaf(f, wo_[(8 + i) * 3 + mm], s[kx][mm]);
            }
        }
        // tree-reduce over the 16 h-chunks (lanes hg within 16-lane groups)
        #pragma unroll
        for (int d = 1; d < 16; d <<= 1)
            #pragma unroll
            for (int kx = 0; kx < 3; ++kx)
                #pragma unroll
                for (int mm = 0; mm < 3; ++mm)
                    s[kx][mm] += __shfl_xor(s[kx][mm], d);

        if (hg == 0) {
            // dc[m*3+kx] = s[kx][m]; out combine per the skew-symmetric A
            const float o0 =  s[1][0] + s[2][1];   // +dc0/dx1 + dc1/dx2
            const float o1 = -s[0][0] + s[2][2];   // -dc0/dx0 + dc2/dx2
            const float o2 = -s[0][1] - s[1][2];   // -dc1/dx0 - dc2/dx1
            float* op = out + (pt0 + p) * 3;
            op[0] = o0; op[1] = o1; op[2] = o2;
        }
    }
}

extern "C" void kernel_launch(void* const* d_in, const int* in_sizes, int n_in,
                              void* d_out, int out_size, void* d_ws, size_t ws_size,
                              hipStream_t stream) {
    const float* x  = (const float*)d_in[0];
    const float* W1 = (const float*)d_in[1];
    const float* b1 = (const float*)d_in[2];
    const float* W2 = (const float*)d_in[3];
    const float* b2 = (const float*)d_in[4];
    const float* W3 = (const float*)d_in[5];
    const float* b3 = (const float*)d_in[6];
    const float* Wo = (const float*)d_in[7];
    // d_in[8] = bo: derivative of a constant -> unused
    unsigned short* Wt = (unsigned short*)d_ws;   // 256 KB: bf16 W2^T, W3^T frags
    const int N = in_sizes[0] / 3;

    hipLaunchKernelGGL(prep_kernel, dim3(256), dim3(64), 0, stream, W2, W3, Wt);
    hipLaunchKernelGGL(divfree_kernel, dim3(N / NPTS), dim3(256), 0, stream,
                       x, W1, b1, W2, b2, W3, b3, Wo, Wt, (float*)d_out);
}